// Round 3
// baseline (211.252 us; speedup 1.0000x reference)
//
#include <hip/hip_runtime.h>

#define DD 5
#define SS 32
#define F_N 100000
#define V_N 60000
#define E_N (F_N * DD)
#define K2_FPB 64
#define K2_T 320

__device__ __forceinline__ float lse2(float a, float b) {
    float m = fmaxf(a, b);
    return m + __logf(__expf(a - m) + __expf(b - m));
}

// ---------------- Kernel 1: factor->var messages + var_beliefs scatter ----------------
// One thread per EDGE (e = f*5 + d). 5 sibling threads redundantly reduce their
// factor's 32 beliefs (L1-shared loads, idle VALU) -> high occupancy.
__global__ __launch_bounds__(256) void k_f2v(
    const float* __restrict__ prv_v2f,   // [E,2]
    const float* __restrict__ prv_f2v,   // [E,2]
    const float* __restrict__ prv_fb,    // [F,32]
    const int*   __restrict__ edge_v,    // [E]
    float* __restrict__ out_f2v,         // [E,2]
    float* __restrict__ out_vb)          // [V,2] (pre-zeroed)
{
    int e = blockIdx.x * blockDim.x + threadIdx.x;
    if (e >= E_N) return;
    int f = e / DD;
    int d = e - f * DD;
    const int shift = 4 - d;

    float fb[SS];
    const float4* rp = (const float4*)(prv_fb + (size_t)f * SS);
    #pragma unroll
    for (int i = 0; i < 8; ++i) {
        float4 v = rp[i];
        fb[4*i+0] = v.x; fb[4*i+1] = v.y; fb[4*i+2] = v.z; fb[4*i+3] = v.w;
    }
    float M = fb[0];
    #pragma unroll
    for (int s = 1; s < SS; ++s) M = fmaxf(M, fb[s]);
    float s0 = 0.f, s1 = 0.f;
    #pragma unroll
    for (int s = 0; s < SS; ++s) {
        float E = __expf(fb[s] - M);
        if ((s >> shift) & 1) s1 += E; else s0 += E;
    }
    float L0 = M + __logf(s0);
    float L1 = M + __logf(s1);

    float2 m = ((const float2*)prv_v2f)[e];
    float2 p = ((const float2*)prv_f2v)[e];
    float a0 = 0.5f * (L0 - m.x) + 0.5f * p.x;
    float a1 = 0.5f * (L1 - m.y) + 0.5f * p.y;
    float z = lse2(a0, a1);
    a0 -= z; a1 -= z;
    ((float2*)out_f2v)[e] = make_float2(a0, a1);

    int v = edge_v[e];
    atomicAdd(out_vb + 2*(size_t)v,     a0);
    atomicAdd(out_vb + 2*(size_t)v + 1, a1);
}

// ---------------- Kernel 2: var->factor messages + factor beliefs (fused MLPs) ----------------
// Block = 320 threads <-> 64 factors (5 threads per factor).
// Phase A: edge-parallel v2f (coalesced). Phase B/C: 5-way-split folded matvecs.
__global__ __launch_bounds__(K2_T) void k_v2f_fb(
    const float* __restrict__ pot,       // [F,32]
    const float* __restrict__ W1, const float* __restrict__ b1,
    const float* __restrict__ W2, const float* __restrict__ b2,
    const float* __restrict__ W3, const float* __restrict__ b3,
    const float* __restrict__ W4, const float* __restrict__ b4,
    const int*   __restrict__ edge_v,    // [E]
    const float* __restrict__ f2v,       // [E,2]
    const float* __restrict__ vb,        // [V,2]
    float* __restrict__ out_v2f,         // [E,2]
    float* __restrict__ out_fb)          // [F,32]
{
    // stride-33 padding on all [.,32]-indexed tiles: lanes differing in row hit
    // distinct banks ((row+col)%32) instead of 5/13-way conflicts at stride 32.
    __shared__ float sW1[SS*33], sW2[SS*33], sb1[SS], sb2[SS];
    __shared__ float sa0[K2_FPB*DD], sa1[K2_FPB*DD];
    __shared__ float sY[K2_FPB*33];
    __shared__ float sO[K2_FPB*33];
    const int t = threadIdx.x;

    // Fold each 2-layer identity-residual MLP into one affine map.
    for (int idx = t; idx < SS*SS; idx += K2_T) {
        const int i = idx >> 5, k = idx & 31;
        float acc1 = 0.f, acc2 = 0.f;
        #pragma unroll
        for (int j = 0; j < SS; ++j) {
            acc1 += W2[i*SS+j] * W1[j*SS+k];
            acc2 += W4[i*SS+j] * W3[j*SS+k];
        }
        sW1[i*33+k] = 0.5f*acc1 + (i == k ? 0.5f : 0.f);
        sW2[i*33+k] = 0.5f*acc2 + (i == k ? 0.5f : 0.f);
    }
    if (t < SS) {
        float a1 = 0.f, a2 = 0.f;
        #pragma unroll
        for (int j = 0; j < SS; ++j) {
            a1 += W2[t*SS+j] * b1[j];
            a2 += W4[t*SS+j] * b3[j];
        }
        sb1[t] = 0.5f * (a1 + b2[t]);
        sb2[t] = 0.5f * (a2 + b4[t]);
    }

    const int fbase = blockIdx.x * K2_FPB;
    const int nf = min(K2_FPB, F_N - fbase);
    const int ne = nf * DD;

    // Phase A: per-edge v2f
    if (t < ne) {
        int e = fbase * DD + t;
        float2 m = ((const float2*)f2v)[e];
        int v = edge_v[e];
        float2 B = ((const float2*)vb)[v];
        float a0 = B.x - m.x, a1 = B.y - m.y;
        float z = lse2(a0, a1);
        a0 -= z; a1 -= z;
        ((float2*)out_v2f)[e] = make_float2(a0, a1);
        sa0[t] = a0; sa1[t] = a1;
    }
    __syncthreads();

    const int fl = t / DD, p = t - fl * DD;

    // Phase B: y = pot + 5*beff1 + x @ Weff1^T   (thread p computes rows p, p+5, ...)
    if (fl < nf) {
        float A0[DD], A1[DD];
        #pragma unroll
        for (int d = 0; d < DD; ++d) { A0[d] = sa0[fl*DD+d]; A1[d] = sa1[fl*DD+d]; }
        float x[SS];
        #pragma unroll
        for (int s = 0; s < SS; ++s) {
            float acc = 0.f;
            #pragma unroll
            for (int d = 0; d < DD; ++d) acc += ((s >> (4-d)) & 1) ? A1[d] : A0[d];
            x[s] = acc;
        }
        const float* potf = pot + (size_t)(fbase + fl) * SS;
        for (int i = p; i < SS; i += DD) {
            float acc = 5.0f * sb1[i] + potf[i];
            #pragma unroll
            for (int k = 0; k < SS; ++k) acc += x[k] * sW1[i*33+k];
            sY[fl*33+i] = acc;
        }
    }
    __syncthreads();

    // Phase C: out = beff2 + y @ Weff2^T
    if (fl < nf) {
        float y[SS];
        #pragma unroll
        for (int k = 0; k < SS; ++k) y[k] = sY[fl*33+k];
        for (int i = p; i < SS; i += DD) {
            float acc = sb2[i];
            #pragma unroll
            for (int k = 0; k < SS; ++k) acc += y[k] * sW2[i*33+k];
            sO[fl*33+i] = acc;
        }
    }
    __syncthreads();

    // coalesced write of the block's [nf,32] output tile
    for (int idx = t; idx < nf * SS; idx += K2_T) {
        int flw = idx >> 5, k = idx & 31;
        out_fb[(size_t)fbase * SS + idx] = sO[flw*33+k];
    }
}

extern "C" void kernel_launch(void* const* d_in, const int* in_sizes, int n_in,
                              void* d_out, int out_size, void* d_ws, size_t ws_size,
                              hipStream_t stream) {
    const float* prv_v2f = (const float*)d_in[0];
    const float* prv_f2v = (const float*)d_in[1];
    const float* prv_fb  = (const float*)d_in[2];
    const float* pot     = (const float*)d_in[3];
    const float* W1 = (const float*)d_in[4];
    const float* b1 = (const float*)d_in[5];
    const float* W2 = (const float*)d_in[6];
    const float* b2 = (const float*)d_in[7];
    const float* W3 = (const float*)d_in[8];
    const float* b3 = (const float*)d_in[9];
    const float* W4 = (const float*)d_in[10];
    const float* b4 = (const float*)d_in[11];
    const int* edge_v = (const int*)d_in[13];

    float* out   = (float*)d_out;
    float* o_v2f = out;                         // [E,2]
    float* o_f2v = out + 2*(size_t)E_N;         // [E,2]
    float* o_fb  = out + 4*(size_t)E_N;         // [F,32]
    float* o_vb  = o_fb + (size_t)F_N * SS;     // [V,2]

    hipMemsetAsync(o_vb, 0, (size_t)V_N * 2 * sizeof(float), stream);

    const int blocks1 = (E_N + 255) / 256;
    k_f2v<<<blocks1, 256, 0, stream>>>(prv_v2f, prv_f2v, prv_fb, edge_v, o_f2v, o_vb);

    const int blocks2 = (F_N + K2_FPB - 1) / K2_FPB;
    k_v2f_fb<<<blocks2, K2_T, 0, stream>>>(pot, W1, b1, W2, b2, W3, b3, W4, b4,
                                           edge_v, o_f2v, o_vb, o_v2f, o_fb);
}

// Round 4
// 202.633 us; speedup vs baseline: 1.0425x; 1.0425x over previous
//
#include <hip/hip_runtime.h>

#define DD 5
#define SS 32
#define F_N 100000
#define V_N 60000
#define E_N (F_N * DD)

// ws layout (floats): [0,1024) Weff2 ; [1024,1056) u21 ; [1056,1216) W21B(row-major [32][5]) ; [1216,1248) const32

__device__ __forceinline__ float lse2(float a, float b) {
    float m = fmaxf(a, b);
    return m + __logf(__expf(a - m) + __expf(b - m));
}

// ---------------- Kernel 0: fold MLP weights + zero var_beliefs ----------------
__global__ __launch_bounds__(256) void k_setup(
    const float* __restrict__ W1, const float* __restrict__ b1,
    const float* __restrict__ W2, const float* __restrict__ b2,
    const float* __restrict__ W3, const float* __restrict__ b3,
    const float* __restrict__ W4, const float* __restrict__ b4,
    float* __restrict__ ws, float* __restrict__ vb)
{
    const int t = threadIdx.x;
    if (blockIdx.x == 0) {
        __shared__ float sE1[SS*SS], sE2[SS*SS], sM[SS*SS], sb1e[SS];
        for (int idx = t; idx < SS*SS; idx += 256) {
            const int i = idx >> 5, k = idx & 31;
            float a1 = 0.f, a2 = 0.f;
            #pragma unroll
            for (int j = 0; j < SS; ++j) {
                a1 += W2[i*SS+j] * W1[j*SS+k];
                a2 += W4[i*SS+j] * W3[j*SS+k];
            }
            sE1[idx] = 0.5f*a1 + (i == k ? 0.5f : 0.f);   // Weff1
            sE2[idx] = 0.5f*a2 + (i == k ? 0.5f : 0.f);   // Weff2
        }
        if (t < SS) {
            float a = 0.f;
            #pragma unroll
            for (int j = 0; j < SS; ++j) a += W2[t*SS+j] * b1[j];
            sb1e[t] = 0.5f * (a + b2[t]);                  // beff1
        }
        __syncthreads();
        for (int idx = t; idx < SS*SS; idx += 256) {
            const int i = idx >> 5, k = idx & 31;
            float m = 0.f;
            #pragma unroll
            for (int j = 0; j < SS; ++j) m += sE2[i*SS+j] * sE1[j*SS+k];
            sM[idx] = m;          // M21 = Weff2 @ Weff1
            ws[idx] = sE2[idx];   // Weff2 out
        }
        __syncthreads();
        if (t < SS) {
            float u = 0.f, wb[DD] = {0.f,0.f,0.f,0.f,0.f};
            #pragma unroll
            for (int s = 0; s < SS; ++s) {
                float m = sM[t*SS+s];
                u += m;
                #pragma unroll
                for (int d = 0; d < DD; ++d) if ((s >> (4-d)) & 1) wb[d] += m;
            }
            ws[1024+t] = u;
            #pragma unroll
            for (int d = 0; d < DD; ++d) ws[1056 + t*DD + d] = wb[d];
            float cv = 0.f, bb = 0.f;
            #pragma unroll
            for (int j = 0; j < SS; ++j) {
                cv += sE2[t*SS+j] * sb1e[j];
                bb += W4[t*SS+j] * b3[j];
            }
            ws[1216+t] = 5.f*cv + 0.5f*(bb + b4[t]);       // const32
        }
    } else {
        const int nb = gridDim.x - 1;
        for (int idx = (blockIdx.x-1)*256 + t; idx < 2*V_N; idx += nb*256)
            vb[idx] = 0.f;
    }
}

// ---------------- Kernel 1: factor->var messages + var_beliefs scatter ----------------
// One thread per EDGE (e = f*5 + d).
__global__ __launch_bounds__(256) void k_f2v(
    const float* __restrict__ prv_v2f,   // [E,2]
    const float* __restrict__ prv_f2v,   // [E,2]
    const float* __restrict__ prv_fb,    // [F,32]
    const int*   __restrict__ edge_v,    // [E]
    float* __restrict__ out_f2v,         // [E,2]
    float* __restrict__ out_vb)          // [V,2] (zeroed by k_setup)
{
    int e = blockIdx.x * blockDim.x + threadIdx.x;
    if (e >= E_N) return;
    int f = e / DD;
    int d = e - f * DD;
    const int shift = 4 - d;

    float fb[SS];
    const float4* rp = (const float4*)(prv_fb + (size_t)f * SS);
    #pragma unroll
    for (int i = 0; i < 8; ++i) {
        float4 v = rp[i];
        fb[4*i+0] = v.x; fb[4*i+1] = v.y; fb[4*i+2] = v.z; fb[4*i+3] = v.w;
    }
    float M = fb[0];
    #pragma unroll
    for (int s = 1; s < SS; ++s) M = fmaxf(M, fb[s]);
    float s0 = 0.f, s1 = 0.f;
    #pragma unroll
    for (int s = 0; s < SS; ++s) {
        float E = __expf(fb[s] - M);
        if ((s >> shift) & 1) s1 += E; else s0 += E;
    }
    float L0 = M + __logf(s0);
    float L1 = M + __logf(s1);

    float2 m = ((const float2*)prv_v2f)[e];
    float2 p = ((const float2*)prv_f2v)[e];
    float a0 = 0.5f * (L0 - m.x) + 0.5f * p.x;
    float a1 = 0.5f * (L1 - m.y) + 0.5f * p.y;
    float z = lse2(a0, a1);
    a0 -= z; a1 -= z;
    ((float2*)out_f2v)[e] = make_float2(a0, a1);

    int v = edge_v[e];
    atomicAdd(out_vb + 2*(size_t)v,     a0);
    atomicAdd(out_vb + 2*(size_t)v + 1, a1);
}

// ---------------- Kernel 2: v2f + factor beliefs, one thread per OUTPUT element ----------------
// 256-thread block = 8 factors x 32 output states. All 32 lanes of a factor-group
// redundantly compute the 5 tiny v2f messages (coalescer dedupes the loads);
// lane i<5 writes v2f. Then out_fb[f,i] = const32[i] + c*u21[i] + W21B[i,:]@delta
// + Weff2[i,:]@pot_f  (LDS stride-33, conflict-free broadcast-free reads).
__global__ __launch_bounds__(256) void k_fb(
    const float* __restrict__ pot,       // [F,32]
    const int*   __restrict__ edge_v,    // [E]
    const float* __restrict__ f2v,       // [E,2]  (from K1)
    const float* __restrict__ vb,        // [V,2]  (from K1)
    const float* __restrict__ ws,        // folded matrices
    float* __restrict__ out_v2f,         // [E,2]
    float* __restrict__ out_fb)          // [F,32]
{
    __shared__ float sW[SS*33], su[SS], sB[SS*DD], sc[SS];
    const int t = threadIdx.x;
    for (int idx = t; idx < SS*SS; idx += 256)
        sW[(idx>>5)*33 + (idx&31)] = ws[idx];
    if (t < 32)                 su[t]     = ws[1024 + t];
    else if (t < 64)            sc[t-32]  = ws[1216 + (t-32)];
    else if (t < 64 + SS*DD)    sB[t-64]  = ws[1056 + (t-64)];
    __syncthreads();

    const int f = blockIdx.x * 8 + (t >> 5);
    const int i = t & 31;

    float c = 0.f, dl[DD], w0[DD], w1[DD];
    #pragma unroll
    for (int d = 0; d < DD; ++d) {
        int e = f * DD + d;
        float2 m = ((const float2*)f2v)[e];
        int v = edge_v[e];
        float2 B = ((const float2*)vb)[v];
        float a0 = B.x - m.x, a1 = B.y - m.y;
        float z = lse2(a0, a1);
        a0 -= z; a1 -= z;
        c += a0; dl[d] = a1 - a0;
        w0[d] = a0; w1[d] = a1;
    }
    if (i < DD)
        ((float2*)out_v2f)[f*DD + i] = make_float2(w0[i], w1[i]);

    float acc = sc[i] + c * su[i];
    #pragma unroll
    for (int d = 0; d < DD; ++d) acc += sB[i*DD+d] * dl[d];
    const float4* pp = (const float4*)(pot + (size_t)f * SS);
    #pragma unroll
    for (int q = 0; q < 8; ++q) {
        float4 pv = pp[q];
        acc += sW[i*33+4*q+0]*pv.x + sW[i*33+4*q+1]*pv.y
             + sW[i*33+4*q+2]*pv.z + sW[i*33+4*q+3]*pv.w;
    }
    out_fb[(size_t)f*SS + i] = acc;
}

extern "C" void kernel_launch(void* const* d_in, const int* in_sizes, int n_in,
                              void* d_out, int out_size, void* d_ws, size_t ws_size,
                              hipStream_t stream) {
    const float* prv_v2f = (const float*)d_in[0];
    const float* prv_f2v = (const float*)d_in[1];
    const float* prv_fb  = (const float*)d_in[2];
    const float* pot     = (const float*)d_in[3];
    const float* W1 = (const float*)d_in[4];
    const float* b1 = (const float*)d_in[5];
    const float* W2 = (const float*)d_in[6];
    const float* b2 = (const float*)d_in[7];
    const float* W3 = (const float*)d_in[8];
    const float* b3 = (const float*)d_in[9];
    const float* W4 = (const float*)d_in[10];
    const float* b4 = (const float*)d_in[11];
    const int* edge_v = (const int*)d_in[13];

    float* out   = (float*)d_out;
    float* o_v2f = out;                         // [E,2]
    float* o_f2v = out + 2*(size_t)E_N;         // [E,2]
    float* o_fb  = out + 4*(size_t)E_N;         // [F,32]
    float* o_vb  = o_fb + (size_t)F_N * SS;     // [V,2]
    float* ws    = (float*)d_ws;                // 1248 floats

    k_setup<<<1 + 470, 256, 0, stream>>>(W1, b1, W2, b2, W3, b3, W4, b4, ws, o_vb);

    const int blocks1 = (E_N + 255) / 256;
    k_f2v<<<blocks1, 256, 0, stream>>>(prv_v2f, prv_f2v, prv_fb, edge_v, o_f2v, o_vb);

    k_fb<<<F_N / 8, 256, 0, stream>>>(pot, edge_v, o_f2v, o_vb, ws, o_v2f, o_fb);
}